// Round 1
// 539.172 us; speedup vs baseline: 1.0096x; 1.0096x over previous
//
#include <hip/hip_runtime.h>
#include <math.h>

// ---------------------------------------------------------------------------
// GCN 2-layer forward on MI355X. Round 9: kill the gather tail.
//   aggfused/agg64 gather loops unified into a single clamped-stride loop
//   (idx = min(idx,end-1), weight zeroed past end) so short rows no longer
//   fall into 2-edge/iter serial tails; edge-record loads for iteration n+1
//   are prefetched while iteration n's row gathers + FMAs execute (breaks the
//   rec -> gather dependence chain). Everything else unchanged from round 8.
// ---------------------------------------------------------------------------

typedef __attribute__((ext_vector_type(8))) short bf16x8;
typedef __attribute__((ext_vector_type(4))) float f32x4;

__device__ inline unsigned short f2bf(float f) {
    union { float f; unsigned int u; } v; v.f = f;
    unsigned int r = v.u + 0x7fffu + ((v.u >> 16) & 1u);  // RNE
    return (unsigned short)(r >> 16);
}
__device__ inline float bf2f_lo(unsigned int u) {
    union { unsigned int u; float f; } v; v.u = u << 16; return v.f;
}
__device__ inline float bf2f_hi(unsigned int u) {
    union { unsigned int u; float f; } v; v.u = u & 0xffff0000u; return v.f;
}

// unpack uint4 (8 bf16) and FMA into acc[8] with weight w
__device__ inline void acc8(float* acc, uint4 q, float w) {
    acc[0] += bf2f_lo(q.x) * w; acc[1] += bf2f_hi(q.x) * w;
    acc[2] += bf2f_lo(q.y) * w; acc[3] += bf2f_hi(q.y) * w;
    acc[4] += bf2f_lo(q.z) * w; acc[5] += bf2f_hi(q.z) * w;
    acc[6] += bf2f_lo(q.w) * w; acc[7] += bf2f_hi(q.w) * w;
}

// ---------------- CSR build ----------------
__global__ __launch_bounds__(256) void deg_rank_kernel(
    const int* __restrict__ dst, int E, int* __restrict__ cnt,
    int* __restrict__ rank) {
    int e = blockIdx.x * blockDim.x + threadIdx.x;
    if (e < E) rank[e] = atomicAdd(&cnt[dst[e]], 1);
}

__global__ __launch_bounds__(256) void scan_part1_kernel(
    const int* __restrict__ cnt, int* __restrict__ bsum, int N) {
    __shared__ int s[256];
    const int tid = threadIdx.x;
    int base = blockIdx.x * 1024 + tid * 4;
    int v = 0;
#pragma unroll
    for (int j = 0; j < 4; ++j)
        if (base + j < N) v += cnt[base + j];
    s[tid] = v;
    __syncthreads();
    for (int off = 128; off > 0; off >>= 1) {
        if (tid < off) s[tid] += s[tid + off];
        __syncthreads();
    }
    if (tid == 0) bsum[blockIdx.x] = s[0];
}

__global__ __launch_bounds__(1024) void scan_part2_kernel(
    const int* __restrict__ bsum, int* __restrict__ boffs, int NB,
    int* __restrict__ row_ptr, int N) {
    __shared__ int s[1024];
    const int tid = threadIdx.x;
    int v = (tid < NB) ? bsum[tid] : 0;
    s[tid] = v;
    __syncthreads();
    for (int off = 1; off < 1024; off <<= 1) {
        int t = (tid >= off) ? s[tid - off] : 0;
        __syncthreads();
        if (tid >= off) s[tid] += t;
        __syncthreads();
    }
    if (tid < NB) boffs[tid] = s[tid] - v;  // exclusive
    if (tid == 1023) row_ptr[N] = s[1023];  // grand total
}

__global__ __launch_bounds__(256) void scan_part3_kernel(
    const int* __restrict__ cnt, const int* __restrict__ boffs,
    int* __restrict__ row_ptr, int N) {
    __shared__ int s[256];
    const int tid = threadIdx.x;
    int base = blockIdx.x * 1024 + tid * 4;
    int c[4];
    int v = 0;
#pragma unroll
    for (int j = 0; j < 4; ++j) {
        c[j] = (base + j < N) ? cnt[base + j] : 0;
        v += c[j];
    }
    s[tid] = v;
    __syncthreads();
    for (int off = 1; off < 256; off <<= 1) {
        int t = (tid >= off) ? s[tid - off] : 0;
        __syncthreads();
        if (tid >= off) s[tid] += t;
        __syncthreads();
    }
    int run = boffs[blockIdx.x] + s[tid] - v;
#pragma unroll
    for (int j = 0; j < 4; ++j) {
        if (base + j < N) {
            row_ptr[base + j] = run;
            run += c[j];
        }
    }
}

// Atomic-free scatter: slot = row_ptr[dst] + rank.
__global__ __launch_bounds__(256) void scatter_kernel(
    const int* __restrict__ src, const int* __restrict__ dst,
    const int* __restrict__ rank, const int* __restrict__ cnt,
    const int* __restrict__ row_ptr, int2* __restrict__ csr_ew, int E) {
    int e = blockIdx.x * blockDim.x + threadIdx.x;
    if (e >= E) return;
    int s = src[e], d = dst[e];
    float w = rsqrtf((float)cnt[s] + 1.0f) * rsqrtf((float)cnt[d] + 1.0f);
    int pos = row_ptr[d] + rank[e];
    int2 rec;
    rec.x = s;
    rec.y = __float_as_int(w);
    csr_ew[pos] = rec;
}

// ------ merged weight cast+transpose: W1t[n][k], W2t[n][k] (bf16) ----------
__global__ __launch_bounds__(256) void castw_kernel(
    const float* __restrict__ W1, const float* __restrict__ W2,
    unsigned short* __restrict__ W1t, unsigned short* __restrict__ W2t) {
    int i = blockIdx.x * 256 + threadIdx.x;
    if (i < 65536) {  // W1: 256x256
        int n = i >> 8, k = i & 255;
        W1t[i] = f2bf(W1[(size_t)k * 256 + n]);
    } else if (i < 65536 + 16384) {  // W2: 256x64 -> W2t[64][256]
        int j = i - 65536;
        int n = j >> 8, k = j & 255;
        W2t[j] = f2bf(W2[(size_t)k * 64 + n]);
    }
}

// ---------------- GEMM1: h1b[M,256] = bf16(x[M,256] @ W1), MFMA -------------
// 128(M) x 256(N) tile, BK=32. Wave w owns cols [64w, 64w+64). 32 MFMA/iter/wave.
__global__ __launch_bounds__(256) void gemm1_kernel(
    const float* __restrict__ A, const unsigned short* __restrict__ Bt,
    unsigned short* __restrict__ C, int M) {
    __shared__ unsigned short As[128][32];   // 8 KB
    __shared__ unsigned short Bs[256][32];   // 16 KB

    const int tid = threadIdx.x;
    const int wave = tid >> 6, lane = tid & 63;
    const int quad = lane >> 4, l15 = lane & 15;
    const int m0 = blockIdx.x * 128;

    f32x4 acc[8][4] = {};

    const int arow = tid >> 1;          // 0..127
    const int akk  = (tid & 1) << 4;    // 0 or 16
    const int gr = m0 + arow;

    for (int k0 = 0; k0 < 256; k0 += 32) {
        float4 a0 = make_float4(0.f,0.f,0.f,0.f), a1 = a0, a2 = a0, a3 = a0;
        if (gr < M) {
            const float* ap = &A[(size_t)gr * 256 + k0 + akk];
            a0 = *(const float4*)&ap[0];
            a1 = *(const float4*)&ap[4];
            a2 = *(const float4*)&ap[8];
            a3 = *(const float4*)&ap[12];
        }
        bf16x8 av0, av1;
        av0[0] = (short)f2bf(a0.x); av0[1] = (short)f2bf(a0.y);
        av0[2] = (short)f2bf(a0.z); av0[3] = (short)f2bf(a0.w);
        av0[4] = (short)f2bf(a1.x); av0[5] = (short)f2bf(a1.y);
        av0[6] = (short)f2bf(a1.z); av0[7] = (short)f2bf(a1.w);
        av1[0] = (short)f2bf(a2.x); av1[1] = (short)f2bf(a2.y);
        av1[2] = (short)f2bf(a2.z); av1[3] = (short)f2bf(a2.w);
        av1[4] = (short)f2bf(a3.x); av1[5] = (short)f2bf(a3.y);
        av1[6] = (short)f2bf(a3.z); av1[7] = (short)f2bf(a3.w);
        *(bf16x8*)&As[arow][akk]     = av0;
        *(bf16x8*)&As[arow][akk + 8] = av1;

        const unsigned short* bsrc = &Bt[(size_t)tid * 256 + k0];
        *(bf16x8*)&Bs[tid][0]  = *(const bf16x8*)&bsrc[0];
        *(bf16x8*)&Bs[tid][8]  = *(const bf16x8*)&bsrc[8];
        *(bf16x8*)&Bs[tid][16] = *(const bf16x8*)&bsrc[16];
        *(bf16x8*)&Bs[tid][24] = *(const bf16x8*)&bsrc[24];
        __syncthreads();

        bf16x8 bfv[4];
#pragma unroll
        for (int nt = 0; nt < 4; ++nt)
            bfv[nt] = *(const bf16x8*)&Bs[wave * 64 + nt * 16 + l15][quad * 8];
#pragma unroll
        for (int mt = 0; mt < 8; ++mt) {
            bf16x8 af = *(const bf16x8*)&As[mt * 16 + l15][quad * 8];
#pragma unroll
            for (int nt = 0; nt < 4; ++nt)
                acc[mt][nt] = __builtin_amdgcn_mfma_f32_16x16x32_bf16(
                    af, bfv[nt], acc[mt][nt], 0, 0, 0);
        }
        __syncthreads();
    }

#pragma unroll
    for (int mt = 0; mt < 8; ++mt) {
#pragma unroll
        for (int nt = 0; nt < 4; ++nt) {
            int gcol = wave * 64 + nt * 16 + l15;
#pragma unroll
            for (int r = 0; r < 4; ++r) {
                int grow = m0 + mt * 16 + quad * 4 + r;
                if (grow < M)
                    C[(size_t)grow * 256 + gcol] = f2bf(acc[mt][nt][r]);
            }
        }
    }
}

// ---- FUSED: h2b = bf16( relu(A h1b + b1) @ W2 ), 16 nodes per block -------
// Phase 1 (per wave, 4 nodes): gather with unified clamped stride-8 loop +
// next-iter edge-record prefetch. Phase 2: 16x64x256 MFMA epilog.
__global__ __launch_bounds__(256) void aggfused_kernel(
    const uint4* __restrict__ h,  // h1b rows = 32 uint4 (256 bf16)
    const int2* __restrict__ ew,
    const int* __restrict__ row_ptr, const int* __restrict__ cnt,
    const float* __restrict__ bias, const unsigned short* __restrict__ W2t,
    unsigned short* __restrict__ h2b, int N) {
    __shared__ unsigned short As[16][264];  // +8 bf16 pad: 2-way-free LDS reads

    const int tid = threadIdx.x;
    const int wave = tid >> 6, lane = tid & 63;
    const int half = lane >> 5;
    const int c = lane & 31;
    const int node0 = blockIdx.x * 16;

    for (int i = 0; i < 4; ++i) {
        const int local = wave * 4 + i;
        const int node = node0 + local;
        float acc[8] = {0.f, 0.f, 0.f, 0.f, 0.f, 0.f, 0.f, 0.f};
        if (node < N) {
            float dv = rsqrtf((float)cnt[node] + 1.0f);
            float w0 = dv * dv;
            // self row (issued early; latency overlaps prologue rec loads)
            uint4 qs = h[(size_t)node * 32 + c];
            const int beg = row_ptr[node], end = row_ptr[node + 1];
            acc8(acc, qs, half == 0 ? w0 : 0.f);
            if (beg < end) {
                const int last = end - 1;
                // prologue: recs for e = beg (clamped)
                int2 r0 = ew[min(beg + half,     last)];
                int2 r1 = ew[min(beg + 2 + half, last)];
                int2 r2 = ew[min(beg + 4 + half, last)];
                int2 r3 = ew[min(beg + 6 + half, last)];
                for (int e = beg; e < end; e += 8) {
                    // weights for current batch (zero past end)
                    float we0 = (e + half     < end) ? __int_as_float(r0.y) : 0.f;
                    float we1 = (e + 2 + half < end) ? __int_as_float(r1.y) : 0.f;
                    float we2 = (e + 4 + half < end) ? __int_as_float(r2.y) : 0.f;
                    float we3 = (e + 6 + half < end) ? __int_as_float(r3.y) : 0.f;
                    // issue current row gathers
                    uint4 q0 = h[(size_t)r0.x * 32 + c];
                    uint4 q1 = h[(size_t)r1.x * 32 + c];
                    uint4 q2 = h[(size_t)r2.x * 32 + c];
                    uint4 q3 = h[(size_t)r3.x * 32 + c];
                    // prefetch next-iter recs (clamped; L2-hot, harmless on last)
                    const int en = e + 8;
                    int2 n0 = ew[min(en + half,     last)];
                    int2 n1 = ew[min(en + 2 + half, last)];
                    int2 n2 = ew[min(en + 4 + half, last)];
                    int2 n3 = ew[min(en + 6 + half, last)];
                    acc8(acc, q0, we0);
                    acc8(acc, q1, we1);
                    acc8(acc, q2, we2);
                    acc8(acc, q3, we3);
                    r0 = n0; r1 = n1; r2 = n2; r3 = n3;
                }
            }
        }
#pragma unroll
        for (int k = 0; k < 8; ++k) acc[k] += __shfl_xor(acc[k], 32, 64);

        if (half == 0) {
            float4 b0 = *(const float4*)&bias[c * 8];
            float4 b1 = *(const float4*)&bias[c * 8 + 4];
            unsigned int o0 = f2bf(fmaxf(acc[0] + b0.x, 0.f));
            unsigned int o1 = f2bf(fmaxf(acc[1] + b0.y, 0.f));
            unsigned int o2 = f2bf(fmaxf(acc[2] + b0.z, 0.f));
            unsigned int o3 = f2bf(fmaxf(acc[3] + b0.w, 0.f));
            unsigned int o4 = f2bf(fmaxf(acc[4] + b1.x, 0.f));
            unsigned int o5 = f2bf(fmaxf(acc[5] + b1.y, 0.f));
            unsigned int o6 = f2bf(fmaxf(acc[6] + b1.z, 0.f));
            unsigned int o7 = f2bf(fmaxf(acc[7] + b1.w, 0.f));
            uint4 ov;
            ov.x = o0 | (o1 << 16);
            ov.y = o2 | (o3 << 16);
            ov.z = o4 | (o5 << 16);
            ov.w = o6 | (o7 << 16);
            *(uint4*)&As[local][c * 8] = ov;
        }
    }
    __syncthreads();

    // Phase 2: D[16 nodes][64 cols] = As[16][256] @ W2t^T. Wave w: cols
    // [16w, 16w+16). 8 MFMAs. B-frags straight from global (L2-hot, 32 KB).
    const int quad = lane >> 4, l15 = lane & 15;
    f32x4 accd = {};
#pragma unroll
    for (int k0 = 0; k0 < 8; ++k0) {
        bf16x8 af = *(const bf16x8*)&As[l15][k0 * 32 + quad * 8];
        bf16x8 bf = *(const bf16x8*)&W2t[(size_t)(wave * 16 + l15) * 256 +
                                         k0 * 32 + quad * 8];
        accd = __builtin_amdgcn_mfma_f32_16x16x32_bf16(af, bf, accd, 0, 0, 0);
    }
#pragma unroll
    for (int r = 0; r < 4; ++r) {
        int node = node0 + quad * 4 + r;
        if (node < N)
            h2b[(size_t)node * 64 + wave * 16 + l15] = f2bf(accd[r]);
    }
}

// ---- out = log_softmax(A h2b + b2), F=64 ----------------------------------
__global__ __launch_bounds__(256) void agg64_kernel(
    const uint4* __restrict__ h,  // row = 8 uint4 (64 bf16)
    const int2* __restrict__ ew, const int* __restrict__ row_ptr,
    const int* __restrict__ cnt, const float* __restrict__ bias,
    float* __restrict__ out, int N) {
    const int node = blockIdx.x * 4 + (threadIdx.x >> 6);
    if (node >= N) return;
    const int lane = threadIdx.x & 63;
    const int g = lane >> 3;
    const int c = lane & 7;

    float dv = rsqrtf((float)cnt[node] + 1.0f);
    float w0 = dv * dv;

    float acc[8] = {0.f, 0.f, 0.f, 0.f, 0.f, 0.f, 0.f, 0.f};
    {
        uint4 q = h[(size_t)node * 8 + c];
        acc8(acc, q, g == 0 ? w0 : 0.f);
    }

    const int beg = row_ptr[node], end = row_ptr[node + 1];
    if (beg < end) {
        const int last = end - 1;
        int2 r0 = ew[min(beg + g,     last)];
        int2 r1 = ew[min(beg + 8 + g, last)];
        for (int e = beg; e < end; e += 16) {
            float wa = (e + g     < end) ? __int_as_float(r0.y) : 0.f;
            float wb = (e + 8 + g < end) ? __int_as_float(r1.y) : 0.f;
            uint4 q0 = h[(size_t)r0.x * 8 + c];
            uint4 q1 = h[(size_t)r1.x * 8 + c];
            const int en = e + 16;
            int2 n0 = ew[min(en + g,     last)];
            int2 n1 = ew[min(en + 8 + g, last)];
            acc8(acc, q0, wa);
            acc8(acc, q1, wb);
            r0 = n0; r1 = n1;
        }
    }

#pragma unroll
    for (int k = 0; k < 8; ++k) {
        acc[k] += __shfl_xor(acc[k], 8, 64);
        acc[k] += __shfl_xor(acc[k], 16, 64);
        acc[k] += __shfl_xor(acc[k], 32, 64);
    }

    float4 b0 = *(const float4*)&bias[c * 8];
    float4 b1 = *(const float4*)&bias[c * 8 + 4];
    float v[8];
    v[0] = acc[0] + b0.x; v[1] = acc[1] + b0.y;
    v[2] = acc[2] + b0.z; v[3] = acc[3] + b0.w;
    v[4] = acc[4] + b1.x; v[5] = acc[5] + b1.y;
    v[6] = acc[6] + b1.z; v[7] = acc[7] + b1.w;

    float m = v[0];
#pragma unroll
    for (int k = 1; k < 8; ++k) m = fmaxf(m, v[k]);
    m = fmaxf(m, __shfl_xor(m, 1, 64));
    m = fmaxf(m, __shfl_xor(m, 2, 64));
    m = fmaxf(m, __shfl_xor(m, 4, 64));
    float s = 0.f;
#pragma unroll
    for (int k = 0; k < 8; ++k) s += expf(v[k] - m);
    s += __shfl_xor(s, 1, 64);
    s += __shfl_xor(s, 2, 64);
    s += __shfl_xor(s, 4, 64);
    float ls = m + logf(s);

    if (g == 0) {
        float4 o0, o1;
        o0.x = v[0] - ls; o0.y = v[1] - ls; o0.z = v[2] - ls; o0.w = v[3] - ls;
        o1.x = v[4] - ls; o1.y = v[5] - ls; o1.z = v[6] - ls; o1.w = v[7] - ls;
        *(float4*)&out[(size_t)node * 64 + c * 8] = o0;
        *(float4*)&out[(size_t)node * 64 + c * 8 + 4] = o1;
    }
}

extern "C" void kernel_launch(void* const* d_in, const int* in_sizes, int n_in,
                              void* d_out, int out_size, void* d_ws, size_t ws_size,
                              hipStream_t stream) {
    const float* x  = (const float*)d_in[0];
    const int*   ei = (const int*)d_in[1];
    const float* W1 = (const float*)d_in[2];
    const float* b1 = (const float*)d_in[3];
    const float* W2 = (const float*)d_in[4];
    const float* b2 = (const float*)d_in[5];
    float* out = (float*)d_out;

    const int N = in_sizes[0] / 256;  // 100000
    const int E = in_sizes[1] / 2;    // 1600000
    const int NP = 102400;
    const int NB = (N + 1023) / 1024;  // scan blocks (98)

    // Workspace layout (bytes; 16B-aligned segments). Total ~90 MB.
    char* ws = (char*)d_ws;
    int*   cnt     = (int*)ws;                 ws += (size_t)NP * 4;
    int*   rank    = (int*)ws;                 ws += (size_t)E * 4;
    int*   row_ptr = (int*)ws;                 ws += (size_t)(NP + 4) * 4;
    int*   bsum    = (int*)ws;                 ws += (size_t)1024 * 4;
    int*   boffs   = (int*)ws;                 ws += (size_t)1024 * 4;
    int2*  csr_ew  = (int2*)ws;                ws += (size_t)E * 8;
    unsigned short* W1t   = (unsigned short*)ws; ws += (size_t)256 * 256 * 2;
    unsigned short* W2t   = (unsigned short*)ws; ws += (size_t)256 * 64 * 2;
    unsigned short* h1b   = (unsigned short*)ws; ws += (size_t)N * 256 * 2;
    unsigned short* h2b   = (unsigned short*)ws; ws += (size_t)N * 64 * 2;

    hipMemsetAsync(cnt, 0, (size_t)N * sizeof(int), stream);

    // CSR build (one atomic pass; scatter is atomic-free)
    deg_rank_kernel<<<(E + 255) / 256, 256, 0, stream>>>(ei + E, E, cnt, rank);
    scan_part1_kernel<<<NB, 256, 0, stream>>>(cnt, bsum, N);
    scan_part2_kernel<<<1, 1024, 0, stream>>>(bsum, boffs, NB, row_ptr, N);
    scan_part3_kernel<<<NB, 256, 0, stream>>>(cnt, boffs, row_ptr, N);
    scatter_kernel<<<(E + 255) / 256, 256, 0, stream>>>(
        ei, ei + E, rank, cnt, row_ptr, csr_ew, E);

    // weight casts (merged)
    castw_kernel<<<(65536 + 16384 + 255) / 256, 256, 0, stream>>>(W1, W2, W1t, W2t);

    // h1b = bf16(x @ W1)
    gemm1_kernel<<<(N + 127) / 128, 256, 0, stream>>>(x, W1t, h1b, N);

    // h2b = bf16( relu(A h1b + b1) @ W2 )  [fused aggregation + GEMM2]
    aggfused_kernel<<<(N + 15) / 16, 256, 0, stream>>>(
        (const uint4*)h1b, csr_ew, row_ptr, cnt, b1, W2t, h2b, N);

    // out = log_softmax(A h2b + b2)
    agg64_kernel<<<(N + 3) / 4, 256, 0, stream>>>(
        (const uint4*)h2b, csr_ew, row_ptr, cnt, b2, out, N);
}